// Round 8
// baseline (392.288 us; speedup 1.0000x reference)
//
#include <hip/hip_runtime.h>
#include <hip/hip_bf16.h>

#define N_NODES 50000
#define N_EDGES 800000
#define HID 64
#define N_GRAPHS 64
#define N_CLASSES 10
#define BN_EPS 1e-5f

typedef unsigned int uint;
typedef unsigned short ushort;
typedef uint uintx4 __attribute__((ext_vector_type(4)));

__device__ __forceinline__ float blo(uint u) { return __uint_as_float(u << 16); }
__device__ __forceinline__ float bhi(uint u) { return __uint_as_float(u & 0xffff0000u); }
__device__ __forceinline__ unsigned short f2b(float f) {
  __hip_bfloat16 h = __float2bfloat16(f);
  return *reinterpret_cast<unsigned short*>(&h);
}

// ---------------- CSR build ----------------

__global__ void k_count_deg(const int* __restrict__ dst, int* __restrict__ deg) {
  int e = blockIdx.x * blockDim.x + threadIdx.x;
  if (e < N_EDGES) atomicAdd(&deg[__builtin_nontemporal_load(&dst[e])], 1);
}

__global__ void k_scan_block(const int* __restrict__ deg, int* __restrict__ rowp,
                             int* __restrict__ bsum, float* __restrict__ dis) {
  __shared__ int s[256];
  int tid = threadIdx.x;
  int i = blockIdx.x * 256 + tid;
  int v = (i < N_NODES) ? deg[i] : 0;
  if (i < N_NODES) dis[i] = rsqrtf((float)v + 1.0f);
  s[tid] = v;
  __syncthreads();
  for (int off = 1; off < 256; off <<= 1) {
    int t = (tid >= off) ? s[tid - off] : 0;
    __syncthreads();
    s[tid] += t;
    __syncthreads();
  }
  if (i < N_NODES) rowp[i] = s[tid] - v;
  if (tid == 255) bsum[blockIdx.x] = s[255];
}

__global__ void k_scan_partials(int* __restrict__ bsum, int nb) {
  __shared__ int s[256];
  int tid = threadIdx.x;
  int v = (tid < nb) ? bsum[tid] : 0;
  s[tid] = v;
  __syncthreads();
  for (int off = 1; off < 256; off <<= 1) {
    int t = (tid >= off) ? s[tid - off] : 0;
    __syncthreads();
    s[tid] += t;
    __syncthreads();
  }
  if (tid < nb) bsum[tid] = s[tid] - v;
}

__global__ void k_scan_finish(int* __restrict__ rowp, const int* __restrict__ bsum,
                              int* __restrict__ cursor) {
  int i = blockIdx.x * blockDim.x + threadIdx.x;
  if (i < N_NODES) {
    int v = rowp[i] + bsum[i >> 8];
    rowp[i] = v;
    cursor[i] = v;
  }
  if (i == 0) rowp[N_NODES] = N_EDGES;
}

// scatter just the 16-bit src per edge, grouped by dst (coef rebuilt in agg)
__global__ void k_fill_edges(const int* __restrict__ ei, int* __restrict__ cursor,
                             ushort* __restrict__ edata) {
  int e = blockIdx.x * blockDim.x + threadIdx.x;
  if (e < N_EDGES) {
    int s = __builtin_nontemporal_load(&ei[e]);
    int d = __builtin_nontemporal_load(&ei[N_EDGES + e]);
    int pos = atomicAdd(&cursor[d], 1);
    edata[pos] = (ushort)s;
  }
}

// ---------------- per-layer ----------------

// out[n][j] = bf16( sum_k bnrelu(in[n][k]) * W[k][j] ), split into 32-feat halves
template <bool IN_BF16>
__global__ __launch_bounds__(256) void k_gemm(const void* __restrict__ inA,
                                              const void* __restrict__ inB,
                                              const float* __restrict__ W,
                                              __hip_bfloat16* __restrict__ outA,
                                              __hip_bfloat16* __restrict__ outB,
                                              float* __restrict__ stats_zero,
                                              const float* __restrict__ stats_in,
                                              const float* __restrict__ gamma,
                                              const float* __restrict__ beta) {
  __shared__ float Al[4][64];
  int tid = threadIdx.x;
  int wid = tid >> 6, f = tid & 63;
  if (blockIdx.x == 0) {
    for (int i = tid; i < 1024; i += 256) stats_zero[i] = 0.0f;
  }
  float Wreg[64];
#pragma unroll
  for (int k = 0; k < 64; ++k) Wreg[k] = W[k * 64 + f];
  float sc = 1.f, sh = 0.f;
  if (stats_in) {
    float s = 0.f, q = 0.f;
#pragma unroll
    for (int c = 0; c < 8; ++c) {
      s += stats_in[c * 128 + f];
      q += stats_in[c * 128 + 64 + f];
    }
    float mu = s * (1.0f / N_NODES);
    float var = q * (1.0f / N_NODES) - mu * mu;
    sc = gamma[f] * rsqrtf(var + BN_EPS);
    sh = beta[f] - mu * sc;
  }
  const ushort* inH = (const ushort*)((f < 32) ? inA : inB);
  __hip_bfloat16* outH = (f < 32) ? outA : outB;
  int fh = f & 31;
  for (int n = blockIdx.x * 4 + wid; n < N_NODES; n += gridDim.x * 4) {
    float av;
    if (IN_BF16) {
      ushort u = __builtin_nontemporal_load(&inH[(n << 5) + fh]);
      av = __uint_as_float((uint)u << 16);
    } else {
      av = ((const float*)inA)[(n << 6) + f];
    }
    if (stats_in) {
      av = fmaf(av, sc, sh);
      av = av > 0.f ? av : 0.f;
    }
    Al[wid][f] = av;  // same-wave LDS: ordered, no barrier
    float acc = 0.f;
    const float4* arow = (const float4*)Al[wid];
#pragma unroll
    for (int k4 = 0; k4 < 16; ++k4) {
      float4 a = arow[k4];
      acc = fmaf(a.x, Wreg[k4 * 4 + 0], acc);
      acc = fmaf(a.y, Wreg[k4 * 4 + 1], acc);
      acc = fmaf(a.z, Wreg[k4 * 4 + 2], acc);
      acc = fmaf(a.w, Wreg[k4 * 4 + 3], acc);
    }
    outH[(n << 5) + fh] = __float2bfloat16(acc);  // cached: gather target
  }
}

// U gather instructions, 16 edges each (64B row = 4 lanes x 16B)
template <int U>
__device__ __forceinline__ void gath16(uint er, const uintx4* __restrict__ hw4,
                                       int l4, int g, float acc[8]) {
  uint e[U];
  uintx4 hv[U];
#pragma unroll
  for (int u = 0; u < U; ++u) e[u] = __shfl(er, u * 16 + g, 64);
#pragma unroll
  for (int u = 0; u < U; ++u) hv[u] = hw4[(e[u] >> 16) * 4 + l4];
#pragma unroll
  for (int u = 0; u < U; ++u) {
    float wv = blo(e[u]);
    acc[0] = fmaf(blo(hv[u].x), wv, acc[0]);
    acc[1] = fmaf(bhi(hv[u].x), wv, acc[1]);
    acc[2] = fmaf(blo(hv[u].y), wv, acc[2]);
    acc[3] = fmaf(bhi(hv[u].y), wv, acc[3]);
    acc[4] = fmaf(blo(hv[u].z), wv, acc[4]);
    acc[5] = fmaf(bhi(hv[u].z), wv, acc[5]);
    acc[6] = fmaf(blo(hv[u].w), wv, acc[6]);
    acc[7] = fmaf(bhi(hv[u].w), wv, acc[7]);
  }
}

__device__ __forceinline__ void do_batch16(uint er, int c, const uintx4* __restrict__ hw4,
                                           int l4, int g, float acc[8]) {
  if (c > 48) {
    gath16<4>(er, hw4, l4, g, acc);
  } else if (c > 32) {
    gath16<3>(er, hw4, l4, g, acc);
  } else if (c > 16) {
    gath16<2>(er, hw4, l4, g, acc);
  } else {
    gath16<1>(er, hw4, l4, g, acc);
  }
}

// Aggregate one 32-feature half: gather target is 3.2MB -> L2-resident.
template <int PASS>
__global__ __launch_bounds__(256, 4) void k_agg_half(
    const __hip_bfloat16* __restrict__ hH, const float* __restrict__ dis,
    const int* __restrict__ rowp, const ushort* __restrict__ edata,
    const float* __restrict__ bias, __hip_bfloat16* __restrict__ actH,
    float* __restrict__ stats) {
  __shared__ float ssum[4][32], ssq[4][32];
  int tid = threadIdx.x;
  int wid = tid >> 6, lane = tid & 63;
  int g = lane >> 2, l4 = lane & 3;
  if (lane < 32) {
    ssum[wid][lane] = 0.f;  // same-wave init; only this wave RMWs its slice
    ssq[wid][lane] = 0.f;
  }
  const uintx4* hw4 = (const uintx4*)hH;
  int stride = gridDim.x * 4;
  int n = blockIdx.x * 4 + wid;
  int p0 = 0, p1 = 0;
  ushort esrc = 0;
  float ds = 0.f;
  if (n < N_NODES) {
    p0 = rowp[n];
    p1 = rowp[n + 1];
    int idx = p0 + lane;
    esrc = (idx < p1) ? __builtin_nontemporal_load(&edata[idx]) : (ushort)0;
    ds = dis[esrc];
  }
  while (n < N_NODES) {
    float dn = dis[n];
    uintx4 hself = hw4[n * 4 + l4];  // early, independent
    // 1-deep prefetch of next node's rowp + edge srcs + their dis
    int nn = n + stride;
    int q0 = 0, q1 = 0;
    ushort nesrc = 0;
    float nds = 0.f;
    if (nn < N_NODES) {
      q0 = rowp[nn];
      q1 = rowp[nn + 1];
      int idx = q0 + lane;
      nesrc = (idx < q1) ? __builtin_nontemporal_load(&edata[idx]) : (ushort)0;
      nds = dis[nesrc];
    }
    uint er = (p0 + lane < p1) ? (((uint)esrc << 16) | (uint)f2b(ds * dn)) : 0u;

    float acc[8] = {0, 0, 0, 0, 0, 0, 0, 0};
    int cnt = p1 - p0;
    do_batch16(er, cnt > 64 ? 64 : cnt, hw4, l4, g, acc);
    for (int pb = p0 + 64; pb < p1; pb += 64) {  // rare (deg > 64)
      int idx = pb + lane;
      ushort es2 = (idx < p1) ? edata[idx] : (ushort)0;
      float ds2 = dis[es2];
      uint er2 = (idx < p1) ? (((uint)es2 << 16) | (uint)f2b(ds2 * dn)) : 0u;
      int c = p1 - pb;
      do_batch16(er2, c > 64 ? 64 : c, hw4, l4, g, acc);
    }
#pragma unroll
    for (int off = 4; off < 64; off <<= 1) {
#pragma unroll
      for (int i = 0; i < 8; ++i) acc[i] += __shfl_xor(acc[i], off, 64);
    }
    if (g == 0) {  // lanes 0..3 hold the 32-feat row
      float dn2 = dn * dn;
      float pre[8];
      pre[0] = fmaf(blo(hself.x), dn2, acc[0]);
      pre[1] = fmaf(bhi(hself.x), dn2, acc[1]);
      pre[2] = fmaf(blo(hself.y), dn2, acc[2]);
      pre[3] = fmaf(bhi(hself.y), dn2, acc[3]);
      pre[4] = fmaf(blo(hself.z), dn2, acc[4]);
      pre[5] = fmaf(bhi(hself.z), dn2, acc[5]);
      pre[6] = fmaf(blo(hself.w), dn2, acc[6]);
      pre[7] = fmaf(bhi(hself.w), dn2, acc[7]);
      const float4* b4 = (const float4*)(bias + PASS * 32);
      float4 bA = b4[l4 * 2], bB = b4[l4 * 2 + 1];
      pre[0] += bA.x; pre[1] += bA.y; pre[2] += bA.z; pre[3] += bA.w;
      pre[4] += bB.x; pre[5] += bB.y; pre[6] += bB.z; pre[7] += bB.w;
      uintx4 st;
      st.x = (uint)f2b(pre[0]) | ((uint)f2b(pre[1]) << 16);
      st.y = (uint)f2b(pre[2]) | ((uint)f2b(pre[3]) << 16);
      st.z = (uint)f2b(pre[4]) | ((uint)f2b(pre[5]) << 16);
      st.w = (uint)f2b(pre[6]) | ((uint)f2b(pre[7]) << 16);
      __builtin_nontemporal_store(st, &((uintx4*)actH)[n * 4 + l4]);
      float* su = &ssum[wid][l4 * 8];
      float* sq = &ssq[wid][l4 * 8];
#pragma unroll
      for (int i = 0; i < 8; ++i) {
        su[i] += pre[i];
        sq[i] = fmaf(pre[i], pre[i], sq[i]);
      }
    }
    n = nn; p0 = q0; p1 = q1; esrc = nesrc; ds = nds;
  }
  __syncthreads();
  if (tid < 32) {
    float s4 = ssum[0][tid] + ssum[1][tid] + ssum[2][tid] + ssum[3][tid];
    float q4 = ssq[0][tid] + ssq[1][tid] + ssq[2][tid] + ssq[3][tid];
    float* sl = stats + (blockIdx.x & 7) * 128 + PASS * 32;  // de-contended
    atomicAdd(&sl[tid], s4);
    atomicAdd(&sl[64 + tid], q4);
  }
}

// ---------------- pool + MLP ----------------

__global__ __launch_bounds__(256) void k_pool(const __hip_bfloat16* __restrict__ actA,
                                              const __hip_bfloat16* __restrict__ actB,
                                              const float* __restrict__ stats_in,
                                              const float* __restrict__ gamma,
                                              const float* __restrict__ beta,
                                              float* __restrict__ pooled) {
  int g = blockIdx.x;
  int tid = threadIdx.x;
  int l16 = tid & 15;  // feats 4*l16 .. 4*l16+3
  int r = tid >> 4;    // 16 row-slices
  float sc[4], sh[4];
#pragma unroll
  for (int i = 0; i < 4; ++i) {
    int f = l16 * 4 + i;
    float s = 0.f, q = 0.f;
#pragma unroll
    for (int c = 0; c < 8; ++c) {
      s += stats_in[c * 128 + f];
      q += stats_in[c * 128 + 64 + f];
    }
    float mu = s * (1.0f / N_NODES);
    float var = q * (1.0f / N_NODES) - mu * mu;
    sc[i] = gamma[f] * rsqrtf(var + BN_EPS);
    sh[i] = beta[f] - mu * sc[i];
  }
  const uint2* src = (l16 < 8) ? (const uint2*)actA : (const uint2*)actB;
  int chunk = l16 & 7;
  int gs = g * N_NODES;
  int start = (gs + 63) >> 6;
  int end = (gs + N_NODES + 63) >> 6;
  float m[4] = {0.f, 0.f, 0.f, 0.f};  // post-ReLU >= 0
  for (int n = start + r; n < end; n += 16) {
    uint2 v = src[n * 8 + chunk];
    m[0] = fmaxf(m[0], fmaf(blo(v.x), sc[0], sh[0]));
    m[1] = fmaxf(m[1], fmaf(bhi(v.x), sc[1], sh[1]));
    m[2] = fmaxf(m[2], fmaf(blo(v.y), sc[2], sh[2]));
    m[3] = fmaxf(m[3], fmaf(bhi(v.y), sc[3], sh[3]));
  }
  __shared__ float sm[16][64];
#pragma unroll
  for (int i = 0; i < 4; ++i) sm[r][l16 * 4 + i] = m[i];
  __syncthreads();
  if (tid < 64) {
    float mm = sm[0][tid];
#pragma unroll
    for (int rr = 1; rr < 16; ++rr) mm = fmaxf(mm, sm[rr][tid]);
    pooled[g * 64 + tid] = mm;
  }
}

__global__ __launch_bounds__(256) void k_final(const float* __restrict__ pooled,
                                               const float* __restrict__ w1,
                                               const float* __restrict__ b1,
                                               const float* __restrict__ w2,
                                               const float* __restrict__ b2,
                                               float* __restrict__ out) {
  __shared__ float P[64 * 64];
  __shared__ float Hd[64 * 64];
  int tid = threadIdx.x;
  for (int i = tid; i < 4096; i += 256) P[i] = pooled[i];
  __syncthreads();
  for (int i = tid; i < 4096; i += 256) {
    int g = i >> 6, j = i & 63;
    float acc = b1[j];
#pragma unroll
    for (int k = 0; k < 64; ++k) acc = fmaf(P[g * 64 + k], w1[k * 64 + j], acc);
    Hd[i] = acc > 0.f ? acc : 0.f;
  }
  __syncthreads();
  for (int i = tid; i < 640; i += 256) {
    int g = i / 10, c = i % 10;
    float acc = b2[c];
#pragma unroll
    for (int k = 0; k < 64; ++k) acc = fmaf(Hd[g * 64 + k], w2[k * 10 + c], acc);
    out[i] = acc;
  }
}

// ---------------- launch ----------------

extern "C" void kernel_launch(void* const* d_in, const int* in_sizes, int n_in,
                              void* d_out, int out_size, void* d_ws, size_t ws_size,
                              hipStream_t stream) {
  const float* x = (const float*)d_in[0];
  const int* ei = (const int*)d_in[1];
  const float* W1 = (const float*)d_in[3];
  const float* b1 = (const float*)d_in[4];
  const float* W2 = (const float*)d_in[5];
  const float* b2 = (const float*)d_in[6];
  const float* W3 = (const float*)d_in[7];
  const float* b3 = (const float*)d_in[8];
  const float* gamma = (const float*)d_in[9];
  const float* beta = (const float*)d_in[10];
  const float* l1w = (const float*)d_in[11];
  const float* l1b = (const float*)d_in[12];
  const float* l2w = (const float*)d_in[13];
  const float* l2b = (const float*)d_in[14];
  float* out = (float*)d_out;

  char* ws = (char*)d_ws;
  size_t off = 0;
  auto alloc = [&](size_t bytes) {
    void* p = ws + off;
    off = (off + bytes + 255) & ~(size_t)255;
    return p;
  };
  int* deg = (int*)alloc(N_NODES * 4);
  int* rowp = (int*)alloc((N_NODES + 1) * 4);
  int* cursor = (int*)alloc(N_NODES * 4);
  int* bsum = (int*)alloc(256 * 4);
  ushort* edata = (ushort*)alloc((size_t)N_EDGES * 2);
  float* dis = (float*)alloc(N_NODES * 4);
  __hip_bfloat16* hA = (__hip_bfloat16*)alloc((size_t)N_NODES * 32 * 2);
  __hip_bfloat16* hB = (__hip_bfloat16*)alloc((size_t)N_NODES * 32 * 2);
  __hip_bfloat16* actA = (__hip_bfloat16*)alloc((size_t)N_NODES * 32 * 2);
  __hip_bfloat16* actB = (__hip_bfloat16*)alloc((size_t)N_NODES * 32 * 2);
  float* statsL0 = (float*)alloc(1024 * 4);
  float* statsL1 = (float*)alloc(1024 * 4);
  float* statsL2 = (float*)alloc(1024 * 4);
  float* pooled = (float*)alloc(4096 * 4);

  int nsb = (N_NODES + 255) / 256;  // 196

  (void)hipMemsetAsync(deg, 0, N_NODES * 4, stream);
  k_count_deg<<<(N_EDGES + 255) / 256, 256, 0, stream>>>(ei + N_EDGES, deg);
  k_scan_block<<<nsb, 256, 0, stream>>>(deg, rowp, bsum, dis);
  k_scan_partials<<<1, 256, 0, stream>>>(bsum, nsb);
  k_scan_finish<<<nsb, 256, 0, stream>>>(rowp, bsum, cursor);
  k_fill_edges<<<(N_EDGES + 255) / 256, 256, 0, stream>>>(ei, cursor, edata);

  // layer 1
  k_gemm<false><<<2048, 256, 0, stream>>>(x, nullptr, W1, hA, hB, statsL0, nullptr, gamma, beta);
  k_agg_half<0><<<2048, 256, 0, stream>>>(hA, dis, rowp, edata, b1, actA, statsL0);
  k_agg_half<1><<<2048, 256, 0, stream>>>(hB, dis, rowp, edata, b1, actB, statsL0);
  // layer 2
  k_gemm<true><<<2048, 256, 0, stream>>>(actA, actB, W2, hA, hB, statsL1, statsL0, gamma, beta);
  k_agg_half<0><<<2048, 256, 0, stream>>>(hA, dis, rowp, edata, b2, actA, statsL1);
  k_agg_half<1><<<2048, 256, 0, stream>>>(hB, dis, rowp, edata, b2, actB, statsL1);
  // layer 3
  k_gemm<true><<<2048, 256, 0, stream>>>(actA, actB, W3, hA, hB, statsL2, statsL1, gamma, beta);
  k_agg_half<0><<<2048, 256, 0, stream>>>(hA, dis, rowp, edata, b3, actA, statsL2);
  k_agg_half<1><<<2048, 256, 0, stream>>>(hB, dis, rowp, edata, b3, actB, statsL2);

  k_pool<<<N_GRAPHS, 256, 0, stream>>>(actA, actB, statsL2, gamma, beta, pooled);
  k_final<<<1, 256, 0, stream>>>(pooled, l1w, l1b, l2w, l2b, out);
}